// Round 3
// baseline (18170.192 us; speedup 1.0000x reference)
//
#include <hip/hip_runtime.h>

#define S   8192
#define HHH 512
#define EE  512
#define G4  2048
#define KT  5
#define NEGV (-10000.0f)
#define SENT 0xFFFFFFFFu   // NaN bit pattern used as "not yet written"

// ---------- helpers ----------
__device__ __forceinline__ float bf2f(unsigned short u) {
  union { unsigned int i; float f; } v; v.i = ((unsigned int)u) << 16; return v.f;
}
__device__ __forceinline__ unsigned short f2bf(float f) {
  union { float f; unsigned int i; } v; v.f = f;
  unsigned int u = v.i;
  unsigned int r = (u + 0x7FFFu + ((u >> 16) & 1u)) >> 16;   // RNE
  return (unsigned short)r;
}
__device__ __forceinline__ float sigmoidf_(float x) { return 1.0f / (1.0f + expf(-x)); }

// ---------- 1. input projections: xp = embed[sent] @ W_ih^T + b (bf16 out) ----------
__global__ __launch_bounds__(256) void ih_gemm(
    const float* __restrict__ embed, const int* __restrict__ sent,
    const float* __restrict__ Wf, const float* __restrict__ bf,
    const float* __restrict__ Wb, const float* __restrict__ bb,
    unsigned short* __restrict__ xpf, unsigned short* __restrict__ xpb)
{
  const int rev = blockIdx.z;
  const float* Wi = rev ? Wb : Wf;
  const float* bi = rev ? bb : bf;
  unsigned short* xp = rev ? xpb : xpf;

  __shared__ float At[16][68];
  __shared__ float Bt[16][68];
  __shared__ int sidx[64];

  const int tid = threadIdx.x;
  const int bm = blockIdx.x * 64;
  const int bn = blockIdx.y * 64;
  if (tid < 64) {
    int m = bm + tid;
    sidx[tid] = sent[rev ? (S - 1 - m) : m];
  }
  __syncthreads();

  const int tx = tid & 15, ty = tid >> 4;
  float acc[4][4];
#pragma unroll
  for (int i = 0; i < 4; i++)
#pragma unroll
    for (int j = 0; j < 4; j++) acc[i][j] = 0.f;

  const int lr = tid >> 2;
  const int lk = (tid & 3) * 4;

  for (int k0 = 0; k0 < EE; k0 += 16) {
    float4 a4 = *(const float4*)(embed + (size_t)sidx[lr] * EE + k0 + lk);
    float4 b4 = *(const float4*)(Wi + (size_t)(bn + lr) * EE + k0 + lk);
    At[lk + 0][lr] = a4.x; At[lk + 1][lr] = a4.y; At[lk + 2][lr] = a4.z; At[lk + 3][lr] = a4.w;
    Bt[lk + 0][lr] = b4.x; Bt[lk + 1][lr] = b4.y; Bt[lk + 2][lr] = b4.z; Bt[lk + 3][lr] = b4.w;
    __syncthreads();
#pragma unroll
    for (int kk = 0; kk < 16; kk++) {
      float4 av = *(const float4*)&At[kk][ty * 4];
      float4 bv = *(const float4*)&Bt[kk][tx * 4];
      float aa[4] = {av.x, av.y, av.z, av.w};
      float bbv[4] = {bv.x, bv.y, bv.z, bv.w};
#pragma unroll
      for (int i = 0; i < 4; i++)
#pragma unroll
        for (int j = 0; j < 4; j++) acc[i][j] += aa[i] * bbv[j];
    }
    __syncthreads();
  }
#pragma unroll
  for (int i = 0; i < 4; i++) {
    int m = bm + ty * 4 + i;
    ushort4 pack;
    unsigned short* ps = (unsigned short*)&pack;
#pragma unroll
    for (int j = 0; j < 4; j++) {
      int n = bn + tx * 4 + j;
      ps[j] = f2bf(acc[i][j] + bi[n]);
    }
    *(ushort4*)(xp + (size_t)m * G4 + bn + tx * 4) = pack;
  }
}

// ---------- 2. sequential scan ----------
// Lane map: u = tid>>4 (unit 0..31), g = (tid>>2)&3 (gate), q = tid&3 (k quarter).
// A unit's 4 gate rows live in ONE wave -> gate finish via shuffles, no LDS.
// W slice pinned in VGPRs (asm). h broadcast via double-buffered LDS, 1 barrier/step.
// Cross-WG handshake: data-as-flag (NaN sentinel) on agent-scope H.
__global__ __launch_bounds__(512, 2) void lstm_scan(
    const float* __restrict__ Whh_f, const float* __restrict__ Whh_b,
    const unsigned short* __restrict__ xp_f, const unsigned short* __restrict__ xp_b,
    const float* __restrict__ h0, const float* __restrict__ c0,
    unsigned* __restrict__ Hf, unsigned* __restrict__ Hb)
{
  const int wg = blockIdx.x;
  const int dir = wg >> 4;
  const int slice = wg & 15;
  const float* W = dir ? Whh_b : Whh_f;
  const unsigned short* xp = dir ? xp_b : xp_f;
  unsigned* H = dir ? Hb : Hf;
  const int U0 = slice * 32;

  const int tid = threadIdx.x;
  const int u = tid >> 4;          // local unit 0..31
  const int g = (tid >> 2) & 3;    // gate 0..3 (i,f,g,o)
  const int q = tid & 3;           // k-quarter
  const int sub = tid & 15;
  const int wl = tid & 63;         // lane within wave
  const int grow = g * HHH + U0 + u;

  // W slice resident in 128 VGPRs — pinned
  float4 w4[32];
  {
    const float4* wsrc = (const float4*)(W + (size_t)grow * HHH + q * 128);
#pragma unroll
    for (int k = 0; k < 32; k++) w4[k] = wsrc[k];
  }
#pragma unroll
  for (int k = 0; k < 32; k++) {
    asm volatile("" : "+v"(w4[k].x), "+v"(w4[k].y), "+v"(w4[k].z), "+v"(w4[k].w));
  }

  __shared__ float h_lds[2][4 * 132];   // double-buffered, q-regions padded by 4

  float c_reg = (sub == 0) ? c0[dir * HHH + U0 + u] : 0.f;

  for (int t = 0; t < S; ++t) {
    const int buf = t & 1;
    // prefetch this step's xp for my (u,g) — independent of h, issues early
    unsigned short rx = 0;
    if (q == 0) rx = xp[(size_t)t * G4 + g * HHH + U0 + u];

    if (t > 0) {
      // every lane polls its own element of h[t-1]; the poll IS the load
      const unsigned* src = &H[(size_t)(t - 1) * HHH + tid];
      unsigned v = __hip_atomic_load(src, __ATOMIC_RELAXED, __HIP_MEMORY_SCOPE_AGENT);
      while (v == SENT) {
        unsigned a = __hip_atomic_load(src, __ATOMIC_RELAXED, __HIP_MEMORY_SCOPE_AGENT);
        unsigned b = __hip_atomic_load(src, __ATOMIC_RELAXED, __HIP_MEMORY_SCOPE_AGENT);
        unsigned c = __hip_atomic_load(src, __ATOMIC_RELAXED, __HIP_MEMORY_SCOPE_AGENT);
        unsigned d = __hip_atomic_load(src, __ATOMIC_RELAXED, __HIP_MEMORY_SCOPE_AGENT);
        v = a;
        if (v == SENT) v = b;
        if (v == SENT) v = c;
        if (v == SENT) v = d;
      }
      union { unsigned u; float f; } cv; cv.u = v;
      h_lds[buf][(tid >> 7) * 132 + (tid & 127)] = cv.f;
    } else {
      h_lds[buf][(tid >> 7) * 132 + (tid & 127)] = h0[dir * HHH + tid];
    }
    __syncthreads();   // the only barrier per step

    // matvec: 128 MACs from pinned registers
    float acc = 0.f;
    const float4* hp = (const float4*)&h_lds[buf][q * 132];
#pragma unroll
    for (int k = 0; k < 32; k++) {
      float4 h4 = hp[k];
      acc += w4[k].x * h4.x;
      acc += w4[k].y * h4.y;
      acc += w4[k].z * h4.z;
      acc += w4[k].w * h4.w;
    }
    // reduce across k-quarters (q dimension, in-wave)
    acc += __shfl_xor(acc, 1);
    acc += __shfl_xor(acc, 2);
    // q==0 lane of each (u,g) now holds the full gate sum; add xp there
    float pre = acc + bf2f(rx);
    // gather the 4 gate preactivations to the unit lane (sub==0), in-wave
    const int base = wl & 48;
    float pi = __shfl(pre, base + 0);
    float pf = __shfl(pre, base + 4);
    float pg = __shfl(pre, base + 8);
    float po = __shfl(pre, base + 12);

    if (sub == 0) {
      float i_ = sigmoidf_(pi);
      float f_ = sigmoidf_(pf);
      float g_ = tanhf(pg);
      float o_ = sigmoidf_(po);
      c_reg = f_ * c_reg + i_ * g_;
      float h = o_ * tanhf(c_reg);
      union { float f; unsigned u; } cv; cv.f = h;
      __hip_atomic_store(&H[(size_t)t * HHH + U0 + u], cv.u, __ATOMIC_RELAXED,
                         __HIP_MEMORY_SCOPE_AGENT);
    }
    // no tail barrier: next step writes the other h_lds buffer, and a wave can
    // only pass barrier t+1 after ALL waves finished reading buffer t.
  }
}

// ---------- 3. feats[t] = [Hf[t] | Hb[S-1-t]] @ W_out^T + b_out ----------
__global__ __launch_bounds__(256) void feats_kernel(
    const float* __restrict__ Hf, const float* __restrict__ Hb,
    const float* __restrict__ Wo, const float* __restrict__ bo,
    float* __restrict__ feats)
{
  const int t = blockIdx.x * 4 + (threadIdx.x >> 6);
  const int lane = threadIdx.x & 63;
  float p0 = 0, p1 = 0, p2 = 0, p3 = 0, p4 = 0;
#pragma unroll
  for (int i = 0; i < 16; i++) {
    int j = lane + i * 64;
    float hv = (i < 8) ? Hf[(size_t)t * HHH + j]
                       : Hb[(size_t)(S - 1 - t) * HHH + (j - HHH)];
    p0 += Wo[0 * 1024 + j] * hv;
    p1 += Wo[1 * 1024 + j] * hv;
    p2 += Wo[2 * 1024 + j] * hv;
    p3 += Wo[3 * 1024 + j] * hv;
    p4 += Wo[4 * 1024 + j] * hv;
  }
#pragma unroll
  for (int off = 32; off; off >>= 1) {
    p0 += __shfl_xor(p0, off);
    p1 += __shfl_xor(p1, off);
    p2 += __shfl_xor(p2, off);
    p3 += __shfl_xor(p3, off);
    p4 += __shfl_xor(p4, off);
  }
  if (lane == 0) {
    float* f = feats + (size_t)t * KT;
    f[0] = p0 + bo[0]; f[1] = p1 + bo[1]; f[2] = p2 + bo[2];
    f[3] = p3 + bo[3]; f[4] = p4 + bo[4];
  }
}

// ---------- 4. Viterbi DP (5 lanes) + parallel backtrack via map composition ----------
__device__ __forceinline__ unsigned comp_map(unsigned f, unsigned gmap) {
  unsigned h = 0;
#pragma unroll
  for (int j = 0; j < 5; j++) {
    unsigned gj = (gmap >> (4 * j)) & 15u;
    unsigned fg = (f >> (4 * gj)) & 15u;
    h |= fg << (4 * j);
  }
  return h;
}

__global__ __launch_bounds__(256) void viterbi_kernel(
    const float* __restrict__ feats, const float* __restrict__ T,
    float* __restrict__ out)
{
  __shared__ unsigned char bp_lds[S * 5];
  __shared__ unsigned maps[256];
  __shared__ int best_s;

  const int tid = threadIdx.x;

  if (tid < 5) {
    const int n = tid;
    float Tr0 = T[n * 5 + 0], Tr1 = T[n * 5 + 1], Tr2 = T[n * 5 + 2],
          Tr3 = T[n * 5 + 3], Tr4 = T[n * 5 + 4];
    float T4 = T[4 * 5 + n];
    float fv = (n == 3) ? 0.f : NEGV;
    float cur[8], nxt[8];
#pragma unroll
    for (int i = 0; i < 8; i++) cur[i] = feats[i * 5 + n];
    for (int t0 = 0; t0 < S; t0 += 8) {
#pragma unroll
      for (int i = 0; i < 8; i++) {
        int tn = t0 + 8 + i;
        nxt[i] = (tn < S) ? feats[tn * 5 + n] : 0.f;
      }
#pragma unroll
      for (int i = 0; i < 8; i++) {
        int t = t0 + i;
        float s0 = __shfl(fv, 0) + Tr0;
        float s1 = __shfl(fv, 1) + Tr1;
        float s2 = __shfl(fv, 2) + Tr2;
        float s3 = __shfl(fv, 3) + Tr3;
        float s4 = __shfl(fv, 4) + Tr4;
        float best = s0; int b = 0;
        if (s1 > best) { best = s1; b = 1; }
        if (s2 > best) { best = s2; b = 2; }
        if (s3 > best) { best = s3; b = 3; }
        if (s4 > best) { best = s4; b = 4; }
        fv = best + cur[i];
        bp_lds[t * 5 + n] = (unsigned char)b;
      }
#pragma unroll
      for (int i = 0; i < 8; i++) cur[i] = nxt[i];
    }
    float term = fv + T4;
    float t0v = __shfl(term, 0), t1v = __shfl(term, 1), t2v = __shfl(term, 2),
          t3v = __shfl(term, 3), t4v = __shfl(term, 4);
    float bbest = t0v; int bt = 0;
    if (t1v > bbest) { bbest = t1v; bt = 1; }
    if (t2v > bbest) { bbest = t2v; bt = 2; }
    if (t3v > bbest) { bbest = t3v; bt = 3; }
    if (t4v > bbest) { bbest = t4v; bt = 4; }
    if (n == 0) { out[0] = bbest; best_s = bt; }
  }
  __syncthreads();

  // suffix composition of backpointer maps; a[0] := identity
  unsigned Q = 0x43210u;
  const int d = tid;
  for (int i = 31; i >= 0; i--) {
    int t = d * 32 + i;
    unsigned m;
    if (t == 0) m = 0x43210u;
    else {
      const unsigned char* bp = &bp_lds[t * 5];
      m = (unsigned)bp[0] | ((unsigned)bp[1] << 4) | ((unsigned)bp[2] << 8) |
          ((unsigned)bp[3] << 12) | ((unsigned)bp[4] << 16);
    }
    Q = comp_map(m, Q);
  }
  maps[d] = Q;
  __syncthreads();
#pragma unroll
  for (int off = 1; off < 256; off <<= 1) {
    unsigned mine = maps[d];
    unsigned oth = (d + off < 256) ? maps[d + off] : 0x43210u;
    __syncthreads();
    maps[d] = comp_map(mine, oth);
    __syncthreads();
  }
  unsigned Ex = (d < 255) ? maps[d + 1] : 0x43210u;
  int tag = (Ex >> (4 * best_s)) & 15;
  out[1 + d * 32 + 31] = (float)tag;
  for (int i = 30; i >= 0; i--) {
    int t = d * 32 + i;
    tag = bp_lds[(t + 1) * 5 + tag];
    out[1 + t] = (float)tag;
  }
}

// ---------- launch ----------
extern "C" void kernel_launch(void* const* d_in, const int* in_sizes, int n_in,
                              void* d_out, int out_size, void* d_ws, size_t ws_size,
                              hipStream_t stream)
{
  const int*   sentence = (const int*)d_in[0];
  const float* embed    = (const float*)d_in[1];
  const float* W_ih_f   = (const float*)d_in[2];
  const float* W_hh_f   = (const float*)d_in[3];
  const float* b_f      = (const float*)d_in[4];
  const float* W_ih_b   = (const float*)d_in[5];
  const float* W_hh_b   = (const float*)d_in[6];
  const float* b_b      = (const float*)d_in[7];
  const float* W_out    = (const float*)d_in[8];
  const float* b_out    = (const float*)d_in[9];
  const float* trans    = (const float*)d_in[10];
  const float* h0       = (const float*)d_in[11];
  const float* c0       = (const float*)d_in[12];
  float* out = (float*)d_out;

  char* ws = (char*)d_ws;
  size_t off = 0;
  unsigned short* xp_f = (unsigned short*)(ws + off); off += (size_t)S * G4 * 2;
  unsigned short* xp_b = (unsigned short*)(ws + off); off += (size_t)S * G4 * 2;
  unsigned* Hf = (unsigned*)(ws + off); off += (size_t)S * HHH * 4;
  unsigned* Hb = (unsigned*)(ws + off); off += (size_t)S * HHH * 4;
  float* feats = (float*)(ws + off); off += (size_t)S * KT * 4;
  if (ws_size < off) return;

  // H must start as the NaN sentinel every call (graph replays don't re-poison)
  hipMemsetAsync(Hf, 0xFF, (size_t)S * HHH * 4 * 2, stream);

  dim3 gg(S / 64, G4 / 64, 2);
  ih_gemm<<<gg, 256, 0, stream>>>(embed, sentence, W_ih_f, b_f, W_ih_b, b_b, xp_f, xp_b);
  lstm_scan<<<32, 512, 0, stream>>>(W_hh_f, W_hh_b, xp_f, xp_b, h0, c0, Hf, Hb);
  feats_kernel<<<S / 4, 256, 0, stream>>>((const float*)Hf, (const float*)Hb, W_out, b_out, feats);
  viterbi_kernel<<<1, 256, 0, stream>>>(feats, trans, out);
}

// Round 4
// 16391.833 us; speedup vs baseline: 1.1085x; 1.1085x over previous
//
#include <hip/hip_runtime.h>

#define S   8192
#define HHH 512
#define EE  512
#define G4  2048
#define KT  5
#define NEGV (-10000.0f)
#define SENT 0xFFFFFFFFu   // NaN bit pattern used as "not yet written"

// ---------- helpers ----------
__device__ __forceinline__ float bf2f(unsigned short u) {
  union { unsigned int i; float f; } v; v.i = ((unsigned int)u) << 16; return v.f;
}
__device__ __forceinline__ unsigned short f2bf(float f) {
  union { float f; unsigned int i; } v; v.f = f;
  unsigned int u = v.i;
  unsigned int r = (u + 0x7FFFu + ((u >> 16) & 1u)) >> 16;   // RNE
  return (unsigned short)r;
}
__device__ __forceinline__ float sigmoidf_(float x) { return 1.0f / (1.0f + expf(-x)); }

// ---------- 0. pack W_hh -> bf16, permuted so each scan-thread's 64 uints are contiguous ----------
// Wp[wg][tid][j]: wg=dir*32+slice (64), tid=rgrp*16+cseg (256), j=g*16+jj (64)
// value = pack(W[g*512 + slice*16+rgrp][cseg*32+2jj], ... +2jj+1)
__global__ __launch_bounds__(256) void pack_w(
    const float* __restrict__ Wf, const float* __restrict__ Wb,
    unsigned* __restrict__ Wp)
{
  int id = blockIdx.x * 256 + threadIdx.x;     // 0 .. 64*256*64-1
  int j    = id & 63;
  int tid  = (id >> 6) & 255;
  int wg   = id >> 14;
  int dir = wg >> 5, slice = wg & 31;
  int rgrp = tid >> 4, cseg = tid & 15;
  int g = j >> 4, jj = j & 15;
  int U = slice * 16 + rgrp;
  int r = g * HHH + U;
  int c = cseg * 32 + jj * 2;
  const float* W = dir ? Wb : Wf;
  float lo = W[(size_t)r * HHH + c];
  float hi = W[(size_t)r * HHH + c + 1];
  Wp[id] = (unsigned)f2bf(lo) | ((unsigned)f2bf(hi) << 16);
}

// ---------- 1. input projections: xp = embed[sent] @ W_ih^T + b (bf16, PERMUTED cols) ----------
// store col n (0..2047, gate-major) at permuted index p = (n&511)*4 + (n>>9)  [unit*4+gate]
__global__ __launch_bounds__(256) void ih_gemm(
    const float* __restrict__ embed, const int* __restrict__ sent,
    const float* __restrict__ Wf, const float* __restrict__ bf,
    const float* __restrict__ Wb, const float* __restrict__ bb,
    unsigned short* __restrict__ xpf, unsigned short* __restrict__ xpb)
{
  const int rev = blockIdx.z;
  const float* Wi = rev ? Wb : Wf;
  const float* bi = rev ? bb : bf;
  unsigned short* xp = rev ? xpb : xpf;

  __shared__ float At[16][68];
  __shared__ float Bt[16][68];
  __shared__ int sidx[64];

  const int tid = threadIdx.x;
  const int bm = blockIdx.x * 64;
  const int bn = blockIdx.y * 64;
  if (tid < 64) {
    int m = bm + tid;
    sidx[tid] = sent[rev ? (S - 1 - m) : m];
  }
  __syncthreads();

  const int tx = tid & 15, ty = tid >> 4;
  float acc[4][4];
#pragma unroll
  for (int i = 0; i < 4; i++)
#pragma unroll
    for (int j = 0; j < 4; j++) acc[i][j] = 0.f;

  const int lr = tid >> 2;
  const int lk = (tid & 3) * 4;

  for (int k0 = 0; k0 < EE; k0 += 16) {
    float4 a4 = *(const float4*)(embed + (size_t)sidx[lr] * EE + k0 + lk);
    float4 b4 = *(const float4*)(Wi + (size_t)(bn + lr) * EE + k0 + lk);
    At[lk + 0][lr] = a4.x; At[lk + 1][lr] = a4.y; At[lk + 2][lr] = a4.z; At[lk + 3][lr] = a4.w;
    Bt[lk + 0][lr] = b4.x; Bt[lk + 1][lr] = b4.y; Bt[lk + 2][lr] = b4.z; Bt[lk + 3][lr] = b4.w;
    __syncthreads();
#pragma unroll
    for (int kk = 0; kk < 16; kk++) {
      float4 av = *(const float4*)&At[kk][ty * 4];
      float4 bv = *(const float4*)&Bt[kk][tx * 4];
      float aa[4] = {av.x, av.y, av.z, av.w};
      float bbv[4] = {bv.x, bv.y, bv.z, bv.w};
#pragma unroll
      for (int i = 0; i < 4; i++)
#pragma unroll
        for (int j = 0; j < 4; j++) acc[i][j] += aa[i] * bbv[j];
    }
    __syncthreads();
  }
#pragma unroll
  for (int i = 0; i < 4; i++) {
    int m = bm + ty * 4 + i;
#pragma unroll
    for (int j = 0; j < 4; j++) {
      int n = bn + tx * 4 + j;
      int p = ((n & 511) << 2) | (n >> 9);
      xp[(size_t)m * G4 + p] = f2bf(acc[i][j] + bi[n]);
    }
  }
}

// ---------- 2. sequential scan ----------
// 64 WGs x 256 threads. WG = dir*32+slice handles 16 units (U = slice*16 + rgrp).
// Thread (rgrp=tid>>4, cseg=tid&15): 4 gate rows of unit U, k-range [cseg*32, cseg*32+32).
// W: bf16-packed 64 uints/thread, pinned in VGPRs. h: f32, LDS-staged (swizzled), 8xb128/thread.
// Dot reduce: 4-stage shfl_xor butterfly over cseg -> all gates of U land on the lane group.
// Cross-WG handshake: data-as-flag (NaN sentinel) on agent-scope H.
__global__ __launch_bounds__(256, 1) void lstm_scan(
    const unsigned* __restrict__ Wp,
    const unsigned short* __restrict__ xp_f, const unsigned short* __restrict__ xp_b,
    const float* __restrict__ h0, const float* __restrict__ c0,
    unsigned* __restrict__ Hf, unsigned* __restrict__ Hb)
{
  const int wg = blockIdx.x;
  const int dir = wg >> 5;
  const int slice = wg & 31;
  const unsigned short* xp = dir ? xp_b : xp_f;
  unsigned* H = dir ? Hb : Hf;

  const int tid = threadIdx.x;
  const int rgrp = tid >> 4;
  const int cseg = tid & 15;
  const int U = slice * 16 + rgrp;   // global unit 0..511

  // W slice: 64 packed uints, contiguous per thread -> pinned in VGPRs
  unsigned w[64];
  {
    const uint4* ws = (const uint4*)(Wp + ((size_t)wg * 256 + tid) * 64);
#pragma unroll
    for (int k = 0; k < 16; k++) {
      uint4 t4 = ws[k];
      w[4 * k] = t4.x; w[4 * k + 1] = t4.y; w[4 * k + 2] = t4.z; w[4 * k + 3] = t4.w;
    }
  }
#pragma unroll
  for (int k = 0; k < 64; k++) asm volatile("" : "+v"(w[k]));

  // h staging: element e at word (e>>5)*36 + (e&31)  (4-word pad per 32 -> 2-way banks, free)
  __shared__ float hl[2][16 * 36];

  float c_reg = (cseg == 0) ? c0[dir * HHH + U] : 0.f;

  const int e1 = tid, e2 = tid + 256;
  const int d1 = ((e1 >> 5) * 36) + (e1 & 31);
  const int d2 = ((e2 >> 5) * 36) + (e2 & 31);

  for (int t = 0; t < S; ++t) {
    const int buf = t & 1;
    // xp prefetch: the 4 gate preacts of unit U, one ushort4 (permuted layout)
    ushort4 rx4 = {0, 0, 0, 0};
    if (cseg == 0) rx4 = *(const ushort4*)(xp + (size_t)t * G4 + U * 4);

    if (t > 0) {
      const unsigned* s1 = &H[(size_t)(t - 1) * HHH + e1];
      const unsigned* s2 = &H[(size_t)(t - 1) * HHH + e2];
      unsigned v1 = __hip_atomic_load(s1, __ATOMIC_RELAXED, __HIP_MEMORY_SCOPE_AGENT);
      unsigned v2 = __hip_atomic_load(s2, __ATOMIC_RELAXED, __HIP_MEMORY_SCOPE_AGENT);
      while (v1 == SENT) v1 = __hip_atomic_load(s1, __ATOMIC_RELAXED, __HIP_MEMORY_SCOPE_AGENT);
      while (v2 == SENT) v2 = __hip_atomic_load(s2, __ATOMIC_RELAXED, __HIP_MEMORY_SCOPE_AGENT);
      union { unsigned u; float f; } a, b; a.u = v1; b.u = v2;
      hl[buf][d1] = a.f;
      hl[buf][d2] = b.f;
    } else {
      hl[buf][d1] = h0[dir * HHH + e1];
      hl[buf][d2] = h0[dir * HHH + e2];
    }
    __syncthreads();   // the only barrier per step

    // my 32 h values (8 x ds_read_b128, 16-lane broadcast groups, swizzle-clean)
    float4 h4[8];
    {
      const float4* hp = (const float4*)&hl[buf][cseg * 36];
#pragma unroll
      for (int i = 0; i < 8; i++) h4[i] = hp[i];
    }

    float acc0 = 0.f, acc1 = 0.f, acc2 = 0.f, acc3 = 0.f;
#define DOG(ACC, G)                                                          \
    {                                                                        \
      _Pragma("unroll")                                                      \
      for (int jj = 0; jj < 16; jj++) {                                      \
        unsigned ww = w[(G) * 16 + jj];                                      \
        float lo = __uint_as_float(ww << 16);                                \
        float hi = __uint_as_float(ww & 0xffff0000u);                        \
        float hx = (jj & 1) ? h4[jj >> 1].z : h4[jj >> 1].x;                 \
        float hy = (jj & 1) ? h4[jj >> 1].w : h4[jj >> 1].y;                 \
        ACC += lo * hx + hi * hy;                                            \
      }                                                                      \
    }
    DOG(acc0, 0) DOG(acc1, 1) DOG(acc2, 2) DOG(acc3, 3)
#undef DOG

    // butterfly over the 16 cseg lanes
#pragma unroll
    for (int m = 1; m < 16; m <<= 1) {
      acc0 += __shfl_xor(acc0, m);
      acc1 += __shfl_xor(acc1, m);
      acc2 += __shfl_xor(acc2, m);
      acc3 += __shfl_xor(acc3, m);
    }

    if (cseg == 0) {
      float pi = acc0 + bf2f(rx4.x);
      float pf = acc1 + bf2f(rx4.y);
      float pg = acc2 + bf2f(rx4.z);
      float po = acc3 + bf2f(rx4.w);
      float i_ = sigmoidf_(pi);
      float f_ = sigmoidf_(pf);
      float g_ = tanhf(pg);
      float o_ = sigmoidf_(po);
      c_reg = f_ * c_reg + i_ * g_;
      float h = o_ * tanhf(c_reg);
      union { float f; unsigned u; } cv; cv.f = h;
      __hip_atomic_store(&H[(size_t)t * HHH + U], cv.u, __ATOMIC_RELAXED,
                         __HIP_MEMORY_SCOPE_AGENT);
    }
    // no tail barrier: next step fills the other hl buffer; a wave reaches
    // fill(t+2) only after barrier(t+1), i.e. after ALL waves consumed buf.
  }
}

// ---------- 3. feats[t] = [Hf[t] | Hb[S-1-t]] @ W_out^T + b_out ----------
__global__ __launch_bounds__(256) void feats_kernel(
    const float* __restrict__ Hf, const float* __restrict__ Hb,
    const float* __restrict__ Wo, const float* __restrict__ bo,
    float* __restrict__ feats)
{
  const int t = blockIdx.x * 4 + (threadIdx.x >> 6);
  const int lane = threadIdx.x & 63;
  float p0 = 0, p1 = 0, p2 = 0, p3 = 0, p4 = 0;
#pragma unroll
  for (int i = 0; i < 16; i++) {
    int j = lane + i * 64;
    float hv = (i < 8) ? Hf[(size_t)t * HHH + j]
                       : Hb[(size_t)(S - 1 - t) * HHH + (j - HHH)];
    p0 += Wo[0 * 1024 + j] * hv;
    p1 += Wo[1 * 1024 + j] * hv;
    p2 += Wo[2 * 1024 + j] * hv;
    p3 += Wo[3 * 1024 + j] * hv;
    p4 += Wo[4 * 1024 + j] * hv;
  }
#pragma unroll
  for (int off = 32; off; off >>= 1) {
    p0 += __shfl_xor(p0, off);
    p1 += __shfl_xor(p1, off);
    p2 += __shfl_xor(p2, off);
    p3 += __shfl_xor(p3, off);
    p4 += __shfl_xor(p4, off);
  }
  if (lane == 0) {
    float* f = feats + (size_t)t * KT;
    f[0] = p0 + bo[0]; f[1] = p1 + bo[1]; f[2] = p2 + bo[2];
    f[3] = p3 + bo[3]; f[4] = p4 + bo[4];
  }
}

// ---------- 4. Viterbi DP (5 lanes) + parallel backtrack via map composition ----------
__device__ __forceinline__ unsigned comp_map(unsigned f, unsigned gmap) {
  unsigned h = 0;
#pragma unroll
  for (int j = 0; j < 5; j++) {
    unsigned gj = (gmap >> (4 * j)) & 15u;
    unsigned fg = (f >> (4 * gj)) & 15u;
    h |= fg << (4 * j);
  }
  return h;
}

__global__ __launch_bounds__(256) void viterbi_kernel(
    const float* __restrict__ feats, const float* __restrict__ T,
    float* __restrict__ out)
{
  __shared__ unsigned char bp_lds[S * 5];
  __shared__ unsigned maps[256];
  __shared__ int best_s;

  const int tid = threadIdx.x;

  if (tid < 5) {
    const int n = tid;
    float Tr0 = T[n * 5 + 0], Tr1 = T[n * 5 + 1], Tr2 = T[n * 5 + 2],
          Tr3 = T[n * 5 + 3], Tr4 = T[n * 5 + 4];
    float T4 = T[4 * 5 + n];
    float fv = (n == 3) ? 0.f : NEGV;
    float cur[8], nxt[8];
#pragma unroll
    for (int i = 0; i < 8; i++) cur[i] = feats[i * 5 + n];
    for (int t0 = 0; t0 < S; t0 += 8) {
#pragma unroll
      for (int i = 0; i < 8; i++) {
        int tn = t0 + 8 + i;
        nxt[i] = (tn < S) ? feats[tn * 5 + n] : 0.f;
      }
#pragma unroll
      for (int i = 0; i < 8; i++) {
        int t = t0 + i;
        float s0 = __shfl(fv, 0) + Tr0;
        float s1 = __shfl(fv, 1) + Tr1;
        float s2 = __shfl(fv, 2) + Tr2;
        float s3 = __shfl(fv, 3) + Tr3;
        float s4 = __shfl(fv, 4) + Tr4;
        float best = s0; int b = 0;
        if (s1 > best) { best = s1; b = 1; }
        if (s2 > best) { best = s2; b = 2; }
        if (s3 > best) { best = s3; b = 3; }
        if (s4 > best) { best = s4; b = 4; }
        fv = best + cur[i];
        bp_lds[t * 5 + n] = (unsigned char)b;
      }
#pragma unroll
      for (int i = 0; i < 8; i++) cur[i] = nxt[i];
    }
    float term = fv + T4;
    float t0v = __shfl(term, 0), t1v = __shfl(term, 1), t2v = __shfl(term, 2),
          t3v = __shfl(term, 3), t4v = __shfl(term, 4);
    float bbest = t0v; int bt = 0;
    if (t1v > bbest) { bbest = t1v; bt = 1; }
    if (t2v > bbest) { bbest = t2v; bt = 2; }
    if (t3v > bbest) { bbest = t3v; bt = 3; }
    if (t4v > bbest) { bbest = t4v; bt = 4; }
    if (n == 0) { out[0] = bbest; best_s = bt; }
  }
  __syncthreads();

  // suffix composition of backpointer maps; a[0] := identity
  unsigned Q = 0x43210u;
  const int d = tid;
  for (int i = 31; i >= 0; i--) {
    int t = d * 32 + i;
    unsigned m;
    if (t == 0) m = 0x43210u;
    else {
      const unsigned char* bp = &bp_lds[t * 5];
      m = (unsigned)bp[0] | ((unsigned)bp[1] << 4) | ((unsigned)bp[2] << 8) |
          ((unsigned)bp[3] << 12) | ((unsigned)bp[4] << 16);
    }
    Q = comp_map(m, Q);
  }
  maps[d] = Q;
  __syncthreads();
#pragma unroll
  for (int off = 1; off < 256; off <<= 1) {
    unsigned mine = maps[d];
    unsigned oth = (d + off < 256) ? maps[d + off] : 0x43210u;
    __syncthreads();
    maps[d] = comp_map(mine, oth);
    __syncthreads();
  }
  unsigned Ex = (d < 255) ? maps[d + 1] : 0x43210u;
  int tag = (Ex >> (4 * best_s)) & 15;
  out[1 + d * 32 + 31] = (float)tag;
  for (int i = 30; i >= 0; i--) {
    int t = d * 32 + i;
    tag = bp_lds[(t + 1) * 5 + tag];
    out[1 + t] = (float)tag;
  }
}

// ---------- launch ----------
extern "C" void kernel_launch(void* const* d_in, const int* in_sizes, int n_in,
                              void* d_out, int out_size, void* d_ws, size_t ws_size,
                              hipStream_t stream)
{
  const int*   sentence = (const int*)d_in[0];
  const float* embed    = (const float*)d_in[1];
  const float* W_ih_f   = (const float*)d_in[2];
  const float* W_hh_f   = (const float*)d_in[3];
  const float* b_f      = (const float*)d_in[4];
  const float* W_ih_b   = (const float*)d_in[5];
  const float* W_hh_b   = (const float*)d_in[6];
  const float* b_b      = (const float*)d_in[7];
  const float* W_out    = (const float*)d_in[8];
  const float* b_out    = (const float*)d_in[9];
  const float* trans    = (const float*)d_in[10];
  const float* h0       = (const float*)d_in[11];
  const float* c0       = (const float*)d_in[12];
  float* out = (float*)d_out;

  char* ws = (char*)d_ws;
  size_t off = 0;
  unsigned short* xp_f = (unsigned short*)(ws + off); off += (size_t)S * G4 * 2;
  unsigned short* xp_b = (unsigned short*)(ws + off); off += (size_t)S * G4 * 2;
  unsigned* Hf = (unsigned*)(ws + off); off += (size_t)S * HHH * 4;
  unsigned* Hb = (unsigned*)(ws + off); off += (size_t)S * HHH * 4;
  float* feats = (float*)(ws + off); off += (size_t)S * KT * 4;
  unsigned* Wp = (unsigned*)(ws + off); off += (size_t)64 * 256 * 64 * 4;
  if (ws_size < off) return;

  // H must start as the NaN sentinel every call (graph replays don't re-poison)
  hipMemsetAsync(Hf, 0xFF, (size_t)S * HHH * 4 * 2, stream);

  pack_w<<<64 * 256 * 64 / 256, 256, 0, stream>>>(W_hh_f, W_hh_b, Wp);
  dim3 gg(S / 64, G4 / 64, 2);
  ih_gemm<<<gg, 256, 0, stream>>>(embed, sentence, W_ih_f, b_f, W_ih_b, b_b, xp_f, xp_b);
  lstm_scan<<<64, 256, 0, stream>>>(Wp, xp_f, xp_b, h0, c0, Hf, Hb);
  feats_kernel<<<S / 4, 256, 0, stream>>>((const float*)Hf, (const float*)Hb, W_out, b_out, feats);
  viterbi_kernel<<<1, 256, 0, stream>>>(feats, trans, out);
}